// Round 6
// baseline (3916.452 us; speedup 1.0000x reference)
//
#include <hip/hip_runtime.h>
#include <hip/hip_fp16.h>
#include <math.h>

// BatchSpectralLoss: out = lambda_max(A^T A), A = 8192x4096 fp32 (k==1).
// PERSISTENT single-kernel Lanczos (T=16): 512 blocks x 256 thr, 2 blocks/CU
// co-resident (launch_bounds(256,2)). Each thread holds a 16-row x 16-col
// fp16-packed slice of A in 128 VGPRs for the WHOLE run (A read once).
// Grid-wide sync via hand-rolled 2-level device-scope barrier (monotonic
// counters; co-residency guaranteed by occupancy). Per step: block-local
// norm2 (block covers all cols once -> identical value in every block),
// register dots -> su, register w-partials -> private slice, barrier,
// distributed 8-col/block reduce + Lanczos recurrence, barrier. Sturm
// bisection inlined in block 0 at the end.
//
// ws float layout: vb0@0 vb1@4096 vb2@8192 slots@12288(128) su@12544(8192)
//                  bar@20736(64 u32) partials@24576(512x4096)  (~8.5 MB)

#define NROWS 8192
#define NCOLS 4096
#define T_STEPS 16
#define GRID 512
#define RPB 16

__global__ __launch_bounds__(256) void init_kernel(float* __restrict__ ws) {
    int i = blockIdx.x * 256 + threadIdx.x;   // 0..4095
    unsigned h = (unsigned)i * 2654435761u;
    h ^= h >> 16; h *= 2246822519u; h ^= h >> 13;
    ws[4096 + i] = (h & 1u) ? 0.015625f : -0.015625f;  // vb1 = r1 (unit norm)
    ws[i] = 0.f;                                        // vb0 = r0 = 0
    if (i < 128) ws[12288 + i] = 0.f;                   // slots
    if (i < 64) ((unsigned*)(ws + 20736))[i] = 0u;      // barrier counters
}

__device__ __forceinline__ void gbar(unsigned* bar, int grp, int idx) {
    __threadfence();
    __syncthreads();
    if (threadIdx.x == 0) {
        unsigned old = __hip_atomic_fetch_add(&bar[grp], 1u,
                           __ATOMIC_ACQ_REL, __HIP_MEMORY_SCOPE_AGENT);
        if (old == (unsigned)(idx * 16) - 1u)           // last of my 16-block group
            __hip_atomic_fetch_add(&bar[32], 1u,
                __ATOMIC_ACQ_REL, __HIP_MEMORY_SCOPE_AGENT);
        long spin = 0;
        while (__hip_atomic_load(&bar[32], __ATOMIC_ACQUIRE,
                                 __HIP_MEMORY_SCOPE_AGENT) < (unsigned)(idx * 32)) {
            __builtin_amdgcn_s_sleep(1);
            if (++spin > 200000000L) break;             // paranoia: never hang
        }
    }
    __syncthreads();
    __threadfence();
}

__global__ __launch_bounds__(256, 2) void lanczos_persist(const float* __restrict__ A,
                                                          float* __restrict__ ws,
                                                          float* __restrict__ out) {
    float* vbuf[3] = {ws, ws + 4096, ws + 8192};
    float* slots = ws + 12288;
    float* su = ws + 12544;
    unsigned* bar = (unsigned*)(ws + 20736);
    float* partials = ws + 24576;

    const int b = blockIdx.x, tid = threadIdx.x;
    const int lane = tid & 63, wv = tid >> 6;
    const int cA = tid * 8, cB = 2048 + tid * 8;
    const int grp = b >> 4;

    __shared__ float dgrid[4][16];
    __shared__ float red4[4];

    // ---- load my A slice once (fp32 from HBM), pack fp16 into 128 VGPRs ----
    __half2 ah[RPB][8];
#pragma unroll
    for (int r = 0; r < RPB; ++r) {
        const float* rowp = A + (size_t)(b * RPB + r) * NCOLS;
        const float4* pa = (const float4*)(rowp + cA);
        float4 x = pa[0], y = pa[1];
        ah[r][0] = __floats2half2_rn(x.x, x.y);
        ah[r][1] = __floats2half2_rn(x.z, x.w);
        ah[r][2] = __floats2half2_rn(y.x, y.y);
        ah[r][3] = __floats2half2_rn(y.z, y.w);
        const float4* pq = (const float4*)(rowp + cB);
        float4 z = pq[0], w = pq[1];
        ah[r][4] = __floats2half2_rn(z.x, z.y);
        ah[r][5] = __floats2half2_rn(z.z, z.w);
        ah[r][6] = __floats2half2_rn(w.x, w.y);
        ah[r][7] = __floats2half2_rn(w.z, w.w);
    }

    float norm2_prev = 1.f, norm2_cur = 1.f, inv = 1.f;
    int bidx = 0;

    for (int j = 1; j <= T_STEPS; ++j) {
        float* rc = vbuf[j % 3];
        float* rp = vbuf[(j + 2) % 3];
        float* rn = vbuf[(j + 1) % 3];

        // ---- phase 1: norm2 (block-local, identical across blocks) + v ----
        float v[16];
        {
            const float4* ra = (const float4*)(rc + cA);
            float4 x = ra[0], y = ra[1];
            const float4* rb = (const float4*)(rc + cB);
            float4 z = rb[0], w = rb[1];
            v[0]=x.x; v[1]=x.y; v[2]=x.z; v[3]=x.w;
            v[4]=y.x; v[5]=y.y; v[6]=y.z; v[7]=y.w;
            v[8]=z.x; v[9]=z.y; v[10]=z.z; v[11]=z.w;
            v[12]=w.x; v[13]=w.y; v[14]=w.z; v[15]=w.w;
        }
        float nn = 0.f;
#pragma unroll
        for (int i = 0; i < 16; ++i) nn += v[i] * v[i];
#pragma unroll
        for (int off = 32; off; off >>= 1) nn += __shfl_xor(nn, off);
        __syncthreads();                 // red4 free (prev readers past barrier)
        if (lane == 0) red4[wv] = nn;
        __syncthreads();
        norm2_cur = red4[0] + red4[1] + red4[2] + red4[3];
        inv = rsqrtf(fmaxf(norm2_cur, 1e-30f));
#pragma unroll
        for (int i = 0; i < 16; ++i) v[i] *= inv;

        // ---- dots: s_r = A_r . v for my 16 rows ----
#pragma unroll
        for (int r = 0; r < RPB; ++r) {
            float sp = 0.f;
#pragma unroll
            for (int h = 0; h < 8; ++h) {
                float2 f = __half22float2(ah[r][h]);
                sp += f.x * v[2 * h] + f.y * v[2 * h + 1];
            }
#pragma unroll
            for (int off = 32; off; off >>= 1) sp += __shfl_xor(sp, off);
            if (lane == 0) dgrid[wv][r] = sp;
        }
        __syncthreads();
        if (tid < RPB) {
            float s = dgrid[0][tid] + dgrid[1][tid] + dgrid[2][tid] + dgrid[3][tid];
            dgrid[0][tid] = s;           // s_lds
            su[b * RPB + tid] = s;
        }
        __syncthreads();

        // ---- accumulate w-partial from registers ----
        float wacc[16];
#pragma unroll
        for (int i = 0; i < 16; ++i) wacc[i] = 0.f;
#pragma unroll
        for (int r = 0; r < RPB; ++r) {
            float s = dgrid[0][r];
#pragma unroll
            for (int h = 0; h < 8; ++h) {
                float2 f = __half22float2(ah[r][h]);
                wacc[2 * h]     += s * f.x;
                wacc[2 * h + 1] += s * f.y;
            }
        }
        {
            float* pb_ = partials + (size_t)b * NCOLS;
            float4* w4 = (float4*)(pb_ + cA);
            w4[0] = make_float4(wacc[0], wacc[1], wacc[2], wacc[3]);
            w4[1] = make_float4(wacc[4], wacc[5], wacc[6], wacc[7]);
            float4* w5 = (float4*)(pb_ + cB);
            w5[0] = make_float4(wacc[8], wacc[9], wacc[10], wacc[11]);
            w5[1] = make_float4(wacc[12], wacc[13], wacc[14], wacc[15]);
        }
        ++bidx; gbar(bar, grp, bidx);    // barrier A

        if (j == T_STEPS) break;

        // ---- phase 2: alpha (redundant per block), col-reduce + recurrence ----
        float aa = 0.f;
#pragma unroll
        for (int k = 0; k < 32; ++k) { float s = su[tid + 256 * k]; aa += s * s; }
#pragma unroll
        for (int off = 32; off; off >>= 1) aa += __shfl_xor(aa, off);
        if (lane == 0) red4[wv] = aa;
        __syncthreads();
        float alpha = red4[0] + red4[1] + red4[2] + red4[3];

        int col = b * 8 + (tid >> 5);
        int g0 = tid & 31;
        float wsum = 0.f;
#pragma unroll
        for (int k = 0; k < 16; ++k)
            wsum += partials[(size_t)(g0 + 32 * k) * NCOLS + col];
#pragma unroll
        for (int off = 16; off; off >>= 1) wsum += __shfl_xor(wsum, off);
        if (g0 == 0) {
            float cbv = sqrtf(norm2_cur / norm2_prev);  // beta_{j-1}/||r_{j-1}||
            float rv = wsum - alpha * inv * rc[col] - cbv * rp[col];
            rn[col] = rv;
        }
        if (b == 0 && tid == 0) { slots[j] = alpha; slots[64 + j] = norm2_cur; }
        norm2_prev = norm2_cur;
        ++bidx; gbar(bar, grp, bidx);    // barrier B
    }

    // ---- epilogue: block 0 computes alpha_T, then Sturm bisection ----
    if (b == 0) {
        float aa = 0.f;
#pragma unroll
        for (int k = 0; k < 32; ++k) { float s = su[tid + 256 * k]; aa += s * s; }
#pragma unroll
        for (int off = 32; off; off >>= 1) aa += __shfl_xor(aa, off);
        __syncthreads();
        if (lane == 0) red4[wv] = aa;
        __syncthreads();
        if (tid == 0) {
            slots[T_STEPS] = red4[0] + red4[1] + red4[2] + red4[3];
            slots[64 + T_STEPS] = norm2_cur;
        }
        __syncthreads();
        __shared__ float d_s[64], e2_s[64];
        if (tid < 64) {
            d_s[tid] = (tid < T_STEPS) ? slots[1 + tid] : 0.f;
            e2_s[tid] = (tid < T_STEPS - 1) ? slots[64 + tid + 2] : 0.f;
        }
        __syncthreads();
        if (tid < 64) {
            int ln = tid;
            float e_here = sqrtf(e2_s[ln]);
            float e_prev = (ln > 0) ? sqrtf(e2_s[ln - 1]) : 0.f;
            float d = d_s[ln];
            float gersh = (ln < T_STEPS) ? d + e_here + e_prev : 0.f;
            float dmax = (ln < T_STEPS) ? d : 0.f;
#pragma unroll
            for (int off = 32; off; off >>= 1) {
                gersh = fmaxf(gersh, __shfl_xor(gersh, off));
                dmax = fmaxf(dmax, __shfl_xor(dmax, off));
            }
            float lo = dmax, hi = gersh + 1e-3f;
            for (int round = 0; round < 3; ++round) {
                float stepw = (hi - lo) * (1.f / 64.f);
                float x = lo + stepw * (ln + 1);
                double qv = 1.0;
                int cnt = 0;
                for (int i = 0; i < T_STEPS; ++i) {
                    double qi = (double)d_s[i] - (double)x -
                                ((i > 0) ? (double)e2_s[i - 1] / qv : 0.0);
                    if (fabs(qi) < 1e-300) qi = -1e-300;
                    cnt += (qi < 0.0);
                    qv = qi;
                }
                unsigned long long m = __ballot(cnt < T_STEPS);
                if (m) {
                    int hbit = 63 - __clzll(m);
                    lo = lo + stepw * (hbit + 1);
                    hi = lo + stepw;
                } else {
                    hi = lo + stepw;
                }
            }
            if (ln == 0) out[0] = 0.5f * (lo + hi);
        }
    }
}

extern "C" void kernel_launch(void* const* d_in, const int* in_sizes, int n_in,
                              void* d_out, int out_size, void* d_ws, size_t ws_size,
                              hipStream_t stream) {
    const float* A = (const float*)d_in[0];
    float* out = (float*)d_out;
    float* ws = (float*)d_ws;

    init_kernel<<<16, 256, 0, stream>>>(ws);
    lanczos_persist<<<GRID, 256, 0, stream>>>(A, ws, out);
}